// Round 1
// baseline (21704.189 us; speedup 1.0000x reference)
//
#include <hip/hip_runtime.h>
#include <math.h>

// Problem constants
#define B_   128
#define T_   512
#define RR   512   // n_rec = n_out = n_init
#define DTAU 0.2f

// Partition: grid = R_BLOCKS * B_BLOCKS = 256 WGs (1 per CU -> all co-resident)
#define R_BLOCKS 32
#define B_BLOCKS 8
#define R_S 16              // output rows per WG
#define B_T 16              // batches per WG
#define NWG (R_BLOCKS * B_BLOCKS)
#define NTHREADS 512
#define GROUP_SIZE R_BLOCKS // WGs per batch group (must all publish per step)

// Workspace layout (floats):
//   [0        .. 65536)   h0 buffer  [128][512]
//   [65536    .. 131072)  rh buffer  [128][512]
//   at float offset 131072: 256 ints of counters
//     ctr_h[g]  = ints[g*16]        (g = 0..7)   h versions published * GROUP_SIZE
//     ctr_rh[g] = ints[128 + g*16]
#define WS_H0  0
#define WS_RH  65536
#define WS_CTR 131072

__global__ void init_ctrs(float* ws) {
    int* c = (int*)(ws + WS_CTR);
    if (threadIdx.x < 256) c[threadIdx.x] = 0;
}

__global__ __launch_bounds__(NTHREADS, 2)
void rnn_persistent(const float* __restrict__ x,
                    const float* __restrict__ init_state,
                    const float* __restrict__ W_enc,
                    const float* __restrict__ W_wz,
                    const float* __restrict__ W_uz,
                    const float* __restrict__ W_wr,
                    const float* __restrict__ W_ur,
                    const float* __restrict__ W_wh,
                    const float* __restrict__ W_uh,
                    float* __restrict__ h_out,   // d_out: [B][T][RR]
                    float* __restrict__ ws)
{
    const int wg = blockIdx.x;
    const int bg = wg / R_BLOCKS;    // batch group 0..7
    const int rb = wg % R_BLOCKS;    // r-slice 0..31
    const int b0 = bg * B_T;
    const int i0 = rb * R_S;

    float* h0buf = ws + WS_H0;
    float* rhbuf = ws + WS_RH;
    int* ctrs   = (int*)(ws + WS_CTR);
    int* ctr_h  = &ctrs[bg * 16];
    int* ctr_rh = &ctrs[128 + bg * 16];

    // LDS: ~35 KB total (safe under 64 KB static limit)
    __shared__ float sh[B_T][RR];       // h(t) staging in phase A; rh staging in phase B
    __shared__ float h_own[B_T][R_S];   // own-slice h(t) saved across sh overwrite
    __shared__ float z_own[B_T][R_S];   // z gate saved from phase A to phase B
    __shared__ float xw[3][R_S][2];     // W_wz/W_wr/W_wh rows for our slice
    __shared__ float xt[B_T][2];        // x[b][t][:] this step

    const int tid  = threadIdx.x;
    const int wv   = tid >> 6;          // wave 0..7
    const int lane = tid & 63;

    if (tid < R_S) {
        xw[0][tid][0] = W_wz[(i0 + tid) * 2 + 0];
        xw[0][tid][1] = W_wz[(i0 + tid) * 2 + 1];
        xw[1][tid][0] = W_wr[(i0 + tid) * 2 + 0];
        xw[1][tid][1] = W_wr[(i0 + tid) * 2 + 1];
        xw[2][tid][0] = W_wh[(i0 + tid) * 2 + 0];
        xw[2][tid][1] = W_wh[(i0 + tid) * 2 + 1];
    }

    // ---------- h0 = init_state @ W_enc^T (own batches x own slice) ----------
    for (int idx = tid; idx < B_T * (RR / 4); idx += NTHREADS) {
        int b = idx / (RR / 4), kc = idx % (RR / 4);
        ((float4*)&sh[b][0])[kc] =
            ((const float4*)&init_state[(size_t)(b0 + b) * RR])[kc];
    }
    __syncthreads();
    #pragma unroll
    for (int ii = 0; ii < 2; ++ii) {
        int i  = wv * 2 + ii;
        int ig = i0 + i;
        float we[8];
        #pragma unroll
        for (int j = 0; j < 8; ++j) we[j] = W_enc[(size_t)ig * RR + lane + 64 * j];
        for (int b = 0; b < B_T; ++b) {
            float acc = 0.f;
            #pragma unroll
            for (int j = 0; j < 8; ++j) acc += we[j] * sh[b][lane + 64 * j];
            #pragma unroll
            for (int off = 32; off > 0; off >>= 1) acc += __shfl_xor(acc, off, 64);
            if (lane == 0) h0buf[(size_t)(b0 + b) * RR + ig] = acc;
        }
    }
    __syncthreads();
    if (tid == 0) {
        __builtin_amdgcn_fence(__ATOMIC_RELEASE, "agent");
        atomicAdd(ctr_h, 1);
    }

    // ---------- time loop ----------
    for (int t = 0; t < T_; ++t) {
        // ===== phase A: z,r gates. Needs h version t complete. =====
        if (tid == 0) {
            const int target = GROUP_SIZE * (t + 1);
            while (__hip_atomic_load(ctr_h, __ATOMIC_RELAXED,
                                     __HIP_MEMORY_SCOPE_AGENT) < target)
                __builtin_amdgcn_s_sleep(2);
            __builtin_amdgcn_fence(__ATOMIC_ACQUIRE, "agent");
        }
        __syncthreads();

        // stage h(t) for our batches (t==0: h0 buffer, else previous output row)
        for (int idx = tid; idx < B_T * (RR / 4); idx += NTHREADS) {
            int b = idx / (RR / 4), kc = idx % (RR / 4);
            const float* src = (t == 0)
                ? &h0buf[(size_t)(b0 + b) * RR]
                : &h_out[((size_t)(b0 + b) * T_ + (t - 1)) * RR];
            ((float4*)&sh[b][0])[kc] = ((const float4*)src)[kc];
        }
        if (tid < B_T * 2) {
            int b = tid >> 1, c = tid & 1;
            xt[b][c] = x[((size_t)(b0 + b) * T_ + t) * 2 + c];
        }
        __syncthreads();

        // save own-slice h before sh gets reused for rh
        if (tid < B_T * R_S) {
            int b = tid / R_S, i = tid % R_S;
            h_own[b][i] = sh[b][i0 + i];
        }

        #pragma unroll
        for (int ii = 0; ii < 2; ++ii) {
            int i  = wv * 2 + ii;
            int ig = i0 + i;
            float wz[8], wr[8];
            #pragma unroll
            for (int j = 0; j < 8; ++j) wz[j] = W_uz[(size_t)ig * RR + lane + 64 * j];
            #pragma unroll
            for (int j = 0; j < 8; ++j) wr[j] = W_ur[(size_t)ig * RR + lane + 64 * j];
            for (int b = 0; b < B_T; ++b) {
                float az = 0.f, ar = 0.f;
                #pragma unroll
                for (int j = 0; j < 8; ++j) {
                    float hv = sh[b][lane + 64 * j];
                    az += wz[j] * hv;
                    ar += wr[j] * hv;
                }
                #pragma unroll
                for (int off = 32; off > 0; off >>= 1) {
                    az += __shfl_xor(az, off, 64);
                    ar += __shfl_xor(ar, off, 64);
                }
                if (lane == 0) {
                    float hp = sh[b][ig];
                    float xz = xt[b][0] * xw[0][i][0] + xt[b][1] * xw[0][i][1];
                    float xr = xt[b][0] * xw[1][i][0] + xt[b][1] * xw[1][i][1];
                    float z  = 1.f / (1.f + __expf(-(xz + az)));
                    float r  = 1.f / (1.f + __expf(-(xr + ar)));
                    z_own[b][i] = z;
                    rhbuf[(size_t)(b0 + b) * RR + ig] = r * hp;
                }
            }
        }
        __syncthreads();
        if (tid == 0) {
            __builtin_amdgcn_fence(__ATOMIC_RELEASE, "agent");
            atomicAdd(ctr_rh, 1);
            // ===== phase B gate: wait rh version t complete =====
            const int target = GROUP_SIZE * (t + 1);
            while (__hip_atomic_load(ctr_rh, __ATOMIC_RELAXED,
                                     __HIP_MEMORY_SCOPE_AGENT) < target)
                __builtin_amdgcn_s_sleep(2);
            __builtin_amdgcn_fence(__ATOMIC_ACQUIRE, "agent");
        }
        __syncthreads();

        // stage full rh into sh (overwrites h staging; h_own/z_own hold what we need)
        for (int idx = tid; idx < B_T * (RR / 4); idx += NTHREADS) {
            int b = idx / (RR / 4), kc = idx % (RR / 4);
            ((float4*)&sh[b][0])[kc] =
                ((const float4*)&rhbuf[(size_t)(b0 + b) * RR])[kc];
        }
        __syncthreads();

        #pragma unroll
        for (int ii = 0; ii < 2; ++ii) {
            int i  = wv * 2 + ii;
            int ig = i0 + i;
            float wh[8];
            #pragma unroll
            for (int j = 0; j < 8; ++j) wh[j] = W_uh[(size_t)ig * RR + lane + 64 * j];
            for (int b = 0; b < B_T; ++b) {
                float au = 0.f;
                #pragma unroll
                for (int j = 0; j < 8; ++j) au += wh[j] * sh[b][lane + 64 * j];
                #pragma unroll
                for (int off = 32; off > 0; off >>= 1) au += __shfl_xor(au, off, 64);
                if (lane == 0) {
                    float xh = xt[b][0] * xw[2][i][0] + xt[b][1] * xw[2][i][1];
                    float u  = xh + au;
                    float hp = h_own[b][i];
                    float z  = z_own[b][i];
                    float hn = hp + DTAU * (z - 1.f) * (hp - tanhf(u));
                    h_out[((size_t)(b0 + b) * T_ + t) * RR + ig] = hn;
                }
            }
        }
        __syncthreads();
        if (tid == 0) {
            __builtin_amdgcn_fence(__ATOMIC_RELEASE, "agent");
            atomicAdd(ctr_h, 1);   // h version t+1 contribution
        }
    }
}

// ---------------- decoder: Y[m][n] = sum_k H[m][k] * Wd[n][k] ----------------
// M = 65536 (b*T + t), N = 512, K = 512, all fp32
#define DT_M 64
#define DT_N 64
#define DT_K 32

__global__ __launch_bounds__(256)
void decoder_gemm(const float* __restrict__ H, const float* __restrict__ Wd,
                  float* __restrict__ Y)
{
    __shared__ float As[DT_K][DT_M + 1];
    __shared__ float Bs[DT_K][DT_N + 1];
    const int m0 = blockIdx.x * DT_M;
    const int n0 = blockIdx.y * DT_N;
    const int tid = threadIdx.x;
    const int tx = tid % 16, ty = tid / 16;
    float acc[4][4] = {};

    for (int k0 = 0; k0 < RR; k0 += DT_K) {
        #pragma unroll
        for (int l = 0; l < 2; ++l) {
            int idx = tid + l * 256;           // 512 float4 slots: 64 rows x 8
            int row = idx / (DT_K / 4);
            int kc  = idx % (DT_K / 4);
            float4 v = ((const float4*)&H[(size_t)(m0 + row) * RR + k0])[kc];
            As[kc * 4 + 0][row] = v.x; As[kc * 4 + 1][row] = v.y;
            As[kc * 4 + 2][row] = v.z; As[kc * 4 + 3][row] = v.w;
        }
        #pragma unroll
        for (int l = 0; l < 2; ++l) {
            int idx = tid + l * 256;
            int row = idx / (DT_K / 4);
            int kc  = idx % (DT_K / 4);
            float4 v = ((const float4*)&Wd[(size_t)(n0 + row) * RR + k0])[kc];
            Bs[kc * 4 + 0][row] = v.x; Bs[kc * 4 + 1][row] = v.y;
            Bs[kc * 4 + 2][row] = v.z; Bs[kc * 4 + 3][row] = v.w;
        }
        __syncthreads();
        #pragma unroll
        for (int k = 0; k < DT_K; ++k) {
            float a[4], bb[4];
            #pragma unroll
            for (int i2 = 0; i2 < 4; ++i2) a[i2] = As[k][ty * 4 + i2];
            #pragma unroll
            for (int j2 = 0; j2 < 4; ++j2) bb[j2] = Bs[k][tx * 4 + j2];
            #pragma unroll
            for (int i2 = 0; i2 < 4; ++i2)
                #pragma unroll
                for (int j2 = 0; j2 < 4; ++j2)
                    acc[i2][j2] += a[i2] * bb[j2];
        }
        __syncthreads();
    }
    #pragma unroll
    for (int i2 = 0; i2 < 4; ++i2) {
        float4 v = make_float4(acc[i2][0], acc[i2][1], acc[i2][2], acc[i2][3]);
        ((float4*)&Y[(size_t)(m0 + ty * 4 + i2) * RR + n0])[tx] = v;
    }
}

extern "C" void kernel_launch(void* const* d_in, const int* in_sizes, int n_in,
                              void* d_out, int out_size, void* d_ws, size_t ws_size,
                              hipStream_t stream) {
    const float* x          = (const float*)d_in[0];
    const float* init_state = (const float*)d_in[1];
    const float* W_enc      = (const float*)d_in[2];
    const float* W_wz       = (const float*)d_in[3];
    const float* W_uz       = (const float*)d_in[4];
    const float* W_wr       = (const float*)d_in[5];
    const float* W_ur       = (const float*)d_in[6];
    const float* W_wh       = (const float*)d_in[7];
    const float* W_uh       = (const float*)d_in[8];
    const float* W_dec      = (const float*)d_in[9];

    float* h_out = (float*)d_out;                          // [128][512][512]
    float* y_out = (float*)d_out + (size_t)B_ * T_ * RR;   // [128][512][512]
    float* ws    = (float*)d_ws;

    init_ctrs<<<1, 256, 0, stream>>>(ws);
    rnn_persistent<<<NWG, NTHREADS, 0, stream>>>(
        x, init_state, W_enc, W_wz, W_uz, W_wr, W_ur, W_wh, W_uh, h_out, ws);
    decoder_gemm<<<dim3((B_ * T_) / DT_M, RR / DT_N), 256, 0, stream>>>(
        h_out, W_dec, y_out);
}

// Round 2
// 6363.012 us; speedup vs baseline: 3.4110x; 3.4110x over previous
//
#include <hip/hip_runtime.h>
#include <math.h>

#define B_   128
#define T_   512
#define RR   512
#define DTAU 0.2f

#define R_BLOCKS 32
#define B_BLOCKS 8
#define R_S  16
#define B_T  16
#define NWG  (R_BLOCKS * B_BLOCKS)
#define NTHR 256
#define GROUP 32
#define LOSCALE 4096.0f
#define LOINV   (1.0f/4096.0f)

typedef _Float16 f16x8 __attribute__((ext_vector_type(8)));
typedef float f32x4 __attribute__((ext_vector_type(4)));

#define MFMA(A,B,C) __builtin_amdgcn_mfma_f32_16x16x32_f16(A, B, C, 0, 0, 0)

// ws layout in u32 units:
//   [0      .. 65536)  EX_H  : u32[128][512]  (hi f16 | lo' f16 << 16)
//   [65536  .. 131072) EX_RH : u32[128][512]
//   [131072 .. 131328) flags : 256 ints; flag_h[g]=f[g*16], flag_rh[g]=f[128+g*16]
#define EXH_OFF  0
#define EXRH_OFF 65536
#define FLAG_OFF 131072

__global__ void init_ctrs(unsigned int* ws) {
    if (threadIdx.x < 256) ws[FLAG_OFF + threadIdx.x] = 0;
}

__device__ __forceinline__ unsigned long long ald64(const unsigned long long* p) {
    return __hip_atomic_load(p, __ATOMIC_RELAXED, __HIP_MEMORY_SCOPE_AGENT);
}
__device__ __forceinline__ void ast64(unsigned long long* p, unsigned long long v) {
    __hip_atomic_store(p, v, __ATOMIC_RELAXED, __HIP_MEMORY_SCOPE_AGENT);
}

// Load A-fragments (hi + scaled-lo) for one 16x32 K-chunk directly from the
// u32-interleaved exchange plane.  A[m=lane&15][k=(lane>>4)*8+j].
__device__ __forceinline__ void load_frags(const unsigned int* ex, int kbase, int lane,
                                           f16x8& hi, f16x8& lo) {
    int b  = lane & 15;
    int qd = lane >> 4;
    const unsigned long long* p =
        (const unsigned long long*)(ex + (size_t)b * RR + kbase + qd * 8);
    unsigned long long d0 = ald64(p + 0);
    unsigned long long d1 = ald64(p + 1);
    unsigned long long d2 = ald64(p + 2);
    unsigned long long d3 = ald64(p + 3);
    union { f16x8 v; unsigned int u[4]; } H, L;
    unsigned long long d[4] = {d0, d1, d2, d3};
    #pragma unroll
    for (int m = 0; m < 4; ++m) {
        unsigned int e0 = (unsigned int)d[m];
        unsigned int e1 = (unsigned int)(d[m] >> 32);
        H.u[m] = (e0 & 0xffffu) | (e1 << 16);
        L.u[m] = (e0 >> 16) | (e1 & 0xffff0000u);
    }
    hi = H.v; lo = L.v;
}

// Pack 8 contiguous fp32 weights into hi + scaled-lo f16 fragments.
__device__ __forceinline__ void packW(const float* p, f16x8& hi, f16x8& lo) {
    float4 a = *(const float4*)p;
    float4 c = *(const float4*)(p + 4);
    float w[8] = {a.x, a.y, a.z, a.w, c.x, c.y, c.z, c.w};
    f16x8 H, L;
    #pragma unroll
    for (int j = 0; j < 8; ++j) {
        _Float16 h = (_Float16)w[j];
        H[j] = h;
        L[j] = (_Float16)((w[j] - (float)h) * LOSCALE);
    }
    hi = H; lo = L;
}

__device__ __forceinline__ void spin(const int* flag, int target) {
    while (__hip_atomic_load(flag, __ATOMIC_RELAXED, __HIP_MEMORY_SCOPE_AGENT) < target)
        __builtin_amdgcn_s_sleep(2);
    __asm__ volatile("" ::: "memory");   // keep data loads after the spin exits
}

// Pack value as hi|lo' u32, pair adjacent lanes, even lane stores b64 (agent scope).
__device__ __forceinline__ void publish_val(unsigned int* ex, int idx, int ieven, float v) {
    _Float16 vh = (_Float16)v;
    _Float16 vl = (_Float16)((v - (float)vh) * LOSCALE);
    unsigned int pk = (unsigned int)__builtin_bit_cast(unsigned short, vh)
                    | ((unsigned int)__builtin_bit_cast(unsigned short, vl) << 16);
    unsigned int other = (unsigned int)__shfl_xor((int)pk, 1, 64);
    if (ieven) {
        unsigned long long v64 = ((unsigned long long)other << 32) | (unsigned long long)pk;
        ast64((unsigned long long*)(ex + idx), v64);
    }
}

#define RED(g,w,m,n) sred[((((g)*4+(w))*16+(m))*17)+(n)]

__global__ __launch_bounds__(NTHR, 1)
void rnn_persistent(const float* __restrict__ x,
                    const float* __restrict__ init_state,
                    const float* __restrict__ W_enc,
                    const float* __restrict__ W_wz,
                    const float* __restrict__ W_uz,
                    const float* __restrict__ W_wr,
                    const float* __restrict__ W_ur,
                    const float* __restrict__ W_wh,
                    const float* __restrict__ W_uh,
                    float* __restrict__ h_out,   // [B][T][RR]
                    unsigned int* __restrict__ ws)
{
    const int wg = blockIdx.x;
    const int bg = wg & 7;           // batch group 0..7  (same XCD mod-8: perf only)
    const int rb = wg >> 3;          // r-slice 0..31
    const int b0 = bg * B_T;
    const int i0 = rb * R_S;

    unsigned int* exh  = ws + EXH_OFF  + (size_t)b0 * RR;
    unsigned int* exrh = ws + EXRH_OFF + (size_t)b0 * RR;
    int* fl      = (int*)(ws + FLAG_OFF);
    int* flag_h  = fl + bg * 16;
    int* flag_rh = fl + 128 + bg * 16;

    __shared__ float sred[2 * 4 * 16 * 17];

    const int tid  = threadIdx.x;
    const int lane = tid & 63;
    const int wv   = tid >> 6;       // wave 0..3, owns K-slice [wv*128, wv*128+128)
    const int kb   = wv * 128;
    const int qd   = lane >> 4;
    const int nn   = lane & 15;
    const int bq   = tid >> 4;       // batch 0..15 (pointwise mapping)
    const int iq   = tid & 15;       // row-in-slice 0..15
    const int ig   = i0 + iq;

    // per-thread input-projection weights (2-wide GEMV rows)
    const float wz0 = W_wz[ig * 2], wz1 = W_wz[ig * 2 + 1];
    const float wr0 = W_wr[ig * 2], wr1 = W_wr[ig * 2 + 1];
    const float wh0 = W_wh[ig * 2], wh1 = W_wh[ig * 2 + 1];

    // ---------------- encoder: h0 = init_state @ W_enc^T (fp32 exact) ----------------
    {
        float we[4][8];
        const int myrow = i0 + wv * 4;
        #pragma unroll
        for (int ii = 0; ii < 4; ++ii)
            #pragma unroll
            for (int j = 0; j < 8; ++j)
                we[ii][j] = W_enc[(size_t)(myrow + ii) * RR + lane + 64 * j];
        for (int b = 0; b < B_T; ++b) {
            float is[8];
            #pragma unroll
            for (int j = 0; j < 8; ++j)
                is[j] = init_state[(size_t)(b0 + b) * RR + lane + 64 * j];
            #pragma unroll
            for (int ii = 0; ii < 4; ++ii) {
                float acc = 0.f;
                #pragma unroll
                for (int j = 0; j < 8; ++j) acc += we[ii][j] * is[j];
                #pragma unroll
                for (int off = 32; off > 0; off >>= 1) acc += __shfl_xor(acc, off, 64);
                if (lane == 0) RED(0, 0, b, wv * 4 + ii) = acc;
            }
        }
    }
    __syncthreads();
    float hprev = RED(0, 0, bq, iq);
    publish_val(exh, bq * RR + i0 + iq, !(iq & 1), hprev);
    __asm__ volatile("s_waitcnt vmcnt(0)" ::: "memory");
    __syncthreads();
    if (tid == 0)
        __hip_atomic_fetch_add(flag_h, 1, __ATOMIC_RELAXED, __HIP_MEMORY_SCOPE_AGENT);

    // ---------------- pack recurrent weights to B-fragments in registers ----------------
    // B[k=(lane>>4)*8+j][n=lane&15] = W[i0+n][kb + kc*32 + (lane>>4)*8 + j]
    f16x8 wzh[4], wzl[4], wrh[4], wrl[4], whh[4], whl[4];
    #pragma unroll
    for (int kc = 0; kc < 4; ++kc) {
        const int kg = kb + kc * 32 + qd * 8;
        packW(&W_uz[(size_t)(i0 + nn) * RR + kg], wzh[kc], wzl[kc]);
        packW(&W_ur[(size_t)(i0 + nn) * RR + kg], wrh[kc], wrl[kc]);
        packW(&W_uh[(size_t)(i0 + nn) * RR + kg], whh[kc], whl[kc]);
    }

    float zprev = 0.f;

    // ---------------- time loop ----------------
    for (int t = 0; t < T_; ++t) {
        const int target = GROUP * (t + 1);
        // prefetch x[b][t][:] (independent of exchange)
        const float2 xv = ((const float2*)x)[(size_t)(b0 + bq) * T_ + t];

        // ===== phase A: z, r =====
        spin(flag_h, target);
        f16x8 ah[4], al[4];
        #pragma unroll
        for (int kc = 0; kc < 4; ++kc)
            load_frags(exh, kb + kc * 32, lane, ah[kc], al[kc]);

        f32x4 zM = {0,0,0,0}, zC = {0,0,0,0}, rM = {0,0,0,0}, rC = {0,0,0,0};
        #pragma unroll
        for (int kc = 0; kc < 4; ++kc) {
            zM = MFMA(ah[kc], wzh[kc], zM);
            zC = MFMA(ah[kc], wzl[kc], zC);
            zC = MFMA(al[kc], wzh[kc], zC);
            rM = MFMA(ah[kc], wrh[kc], rM);
            rC = MFMA(ah[kc], wrl[kc], rC);
            rC = MFMA(al[kc], wrh[kc], rC);
        }
        #pragma unroll
        for (int rg = 0; rg < 4; ++rg) {
            RED(0, wv, qd * 4 + rg, nn) = zM[rg] + zC[rg] * LOINV;
            RED(1, wv, qd * 4 + rg, nn) = rM[rg] + rC[rg] * LOINV;
        }
        __syncthreads();

        float zsum = 0.f, rsum = 0.f;
        #pragma unroll
        for (int w = 0; w < 4; ++w) { zsum += RED(0, w, bq, iq); rsum += RED(1, w, bq, iq); }
        const float xz = xv.x * wz0 + xv.y * wz1;
        const float xr = xv.x * wr0 + xv.y * wr1;
        const float z = 1.f / (1.f + expf(-(xz + zsum)));
        const float r = 1.f / (1.f + expf(-(xr + rsum)));
        zprev = z;
        publish_val(exrh, bq * RR + i0 + iq, !(iq & 1), r * hprev);
        __asm__ volatile("s_waitcnt vmcnt(0)" ::: "memory");
        __syncthreads();
        if (tid == 0)
            __hip_atomic_fetch_add(flag_rh, 1, __ATOMIC_RELAXED, __HIP_MEMORY_SCOPE_AGENT);

        // ===== phase B: u, h update =====
        spin(flag_rh, target);
        #pragma unroll
        for (int kc = 0; kc < 4; ++kc)
            load_frags(exrh, kb + kc * 32, lane, ah[kc], al[kc]);

        f32x4 uM = {0,0,0,0}, uC = {0,0,0,0};
        #pragma unroll
        for (int kc = 0; kc < 4; ++kc) {
            uM = MFMA(ah[kc], whh[kc], uM);
            uC = MFMA(ah[kc], whl[kc], uC);
            uC = MFMA(al[kc], whh[kc], uC);
        }
        #pragma unroll
        for (int rg = 0; rg < 4; ++rg)
            RED(0, wv, qd * 4 + rg, nn) = uM[rg] + uC[rg] * LOINV;
        __syncthreads();

        float usum = 0.f;
        #pragma unroll
        for (int w = 0; w < 4; ++w) usum += RED(0, w, bq, iq);
        const float u = xv.x * wh0 + xv.y * wh1 + usum;
        const float e2 = expf(-2.f * fabsf(u));
        const float th = copysignf((1.f - e2) / (1.f + e2), u);
        const float hn = hprev + DTAU * (zprev - 1.f) * (hprev - th);
        hprev = hn;
        h_out[((size_t)(b0 + bq) * T_ + t) * RR + i0 + iq] = hn;
        publish_val(exh, bq * RR + i0 + iq, !(iq & 1), hn);
        __asm__ volatile("s_waitcnt vmcnt(0)" ::: "memory");
        __syncthreads();
        if (tid == 0)
            __hip_atomic_fetch_add(flag_h, 1, __ATOMIC_RELAXED, __HIP_MEMORY_SCOPE_AGENT);
    }
}

// ---------------- decoder: Y[m][n] = sum_k H[m][k] * Wd[n][k] (fp32) ----------------
#define DT_M 64
#define DT_N 64
#define DT_K 32

__global__ __launch_bounds__(256)
void decoder_gemm(const float* __restrict__ H, const float* __restrict__ Wd,
                  float* __restrict__ Y)
{
    __shared__ float As[DT_K][DT_M + 1];
    __shared__ float Bs[DT_K][DT_N + 1];
    const int m0 = blockIdx.x * DT_M;
    const int n0 = blockIdx.y * DT_N;
    const int tid = threadIdx.x;
    const int tx = tid % 16, ty = tid / 16;
    float acc[4][4] = {};

    for (int k0 = 0; k0 < RR; k0 += DT_K) {
        #pragma unroll
        for (int l = 0; l < 2; ++l) {
            int idx = tid + l * 256;
            int row = idx / (DT_K / 4);
            int kc  = idx % (DT_K / 4);
            float4 v = ((const float4*)&H[(size_t)(m0 + row) * RR + k0])[kc];
            As[kc * 4 + 0][row] = v.x; As[kc * 4 + 1][row] = v.y;
            As[kc * 4 + 2][row] = v.z; As[kc * 4 + 3][row] = v.w;
        }
        #pragma unroll
        for (int l = 0; l < 2; ++l) {
            int idx = tid + l * 256;
            int row = idx / (DT_K / 4);
            int kc  = idx % (DT_K / 4);
            float4 v = ((const float4*)&Wd[(size_t)(n0 + row) * RR + k0])[kc];
            Bs[kc * 4 + 0][row] = v.x; Bs[kc * 4 + 1][row] = v.y;
            Bs[kc * 4 + 2][row] = v.z; Bs[kc * 4 + 3][row] = v.w;
        }
        __syncthreads();
        #pragma unroll
        for (int k = 0; k < DT_K; ++k) {
            float a[4], bb[4];
            #pragma unroll
            for (int i2 = 0; i2 < 4; ++i2) a[i2] = As[k][ty * 4 + i2];
            #pragma unroll
            for (int j2 = 0; j2 < 4; ++j2) bb[j2] = Bs[k][tx * 4 + j2];
            #pragma unroll
            for (int i2 = 0; i2 < 4; ++i2)
                #pragma unroll
                for (int j2 = 0; j2 < 4; ++j2)
                    acc[i2][j2] += a[i2] * bb[j2];
        }
        __syncthreads();
    }
    #pragma unroll
    for (int i2 = 0; i2 < 4; ++i2) {
        float4 v = make_float4(acc[i2][0], acc[i2][1], acc[i2][2], acc[i2][3]);
        ((float4*)&Y[(size_t)(m0 + ty * 4 + i2) * RR + n0])[tx] = v;
    }
}

extern "C" void kernel_launch(void* const* d_in, const int* in_sizes, int n_in,
                              void* d_out, int out_size, void* d_ws, size_t ws_size,
                              hipStream_t stream) {
    const float* x          = (const float*)d_in[0];
    const float* init_state = (const float*)d_in[1];
    const float* W_enc      = (const float*)d_in[2];
    const float* W_wz       = (const float*)d_in[3];
    const float* W_uz       = (const float*)d_in[4];
    const float* W_wr       = (const float*)d_in[5];
    const float* W_ur       = (const float*)d_in[6];
    const float* W_wh       = (const float*)d_in[7];
    const float* W_uh       = (const float*)d_in[8];
    const float* W_dec      = (const float*)d_in[9];

    float* h_out = (float*)d_out;                          // [128][512][512]
    float* y_out = (float*)d_out + (size_t)B_ * T_ * RR;   // [128][512][512]
    unsigned int* ws = (unsigned int*)d_ws;

    init_ctrs<<<1, 256, 0, stream>>>(ws);
    rnn_persistent<<<NWG, NTHR, 0, stream>>>(
        x, init_state, W_enc, W_wz, W_uz, W_wr, W_ur, W_wh, W_uh, h_out, ws);
    decoder_gemm<<<dim3((B_ * T_) / DT_M, RR / DT_N), 256, 0, stream>>>(
        h_out, W_dec, y_out);
}